// Round 2
// baseline (212.055 us; speedup 1.0000x reference)
//
#include <hip/hip_runtime.h>

typedef unsigned short u16;
typedef unsigned int   u32;

using bf16x8 = __attribute__((ext_vector_type(8))) __bf16;
using f32x4  = __attribute__((ext_vector_type(4))) float;
using f32x16 = __attribute__((ext_vector_type(16))) float;

#define DEV static __device__ __forceinline__
#define GP(p) (const __attribute__((address_space(1))) void*)(p)
#define LP(p) (__attribute__((address_space(3))) void*)(p)
// fused counted-wait + barrier (T4): memory clobber pins LDS/global ops on both sides
#define WAITB(N) asm volatile("s_waitcnt vmcnt(" N ")\n\ts_barrier" ::: "memory")

DEV u16 f2bf(float f){                      // RNE float->bf16
  u32 u = __builtin_bit_cast(u32, f);
  u32 r = u + 0x7fffu + ((u>>16)&1u);
  return (u16)(r>>16);
}
DEV bf16x8 as_bf(uint4 v){ return __builtin_bit_cast(bf16x8, v); }
DEV u32 cvt_pk(float lo, float hi){
  u32 r;
  asm("v_cvt_pk_bf16_f32 %0, %1, %2" : "=v"(r) : "v"(lo), "v"(hi));
  return r;
}
DEV void plswap(u32 &a, u32 &b){
  auto r = __builtin_amdgcn_permlane32_swap((int)a, (int)b, false, false);
  a = (u32)r[0]; b = (u32)r[1];
}
DEV float fexp2(float x){ float r; asm("v_exp_f32 %0, %1" : "=v"(r) : "v"(x)); return r; }
DEV float max3f(float a, float b, float c){
  float r; asm("v_max3_f32 %0, %1, %2, %3" : "=v"(r) : "v"(a), "v"(b), "v"(c)); return r;
}
// sin/cos of (2*pi*x) via HW revolutions path: fract -> v_sin/v_cos (saves __sincosf's
// radian range-reduction VALU; accuracy ~1e-4 rad, far under bf16 output quantum)
DEV float fractf_(float x){ float r; asm("v_fract_f32 %0, %1" : "=v"(r) : "v"(x)); return r; }
DEV float sinrev(float f){ float r; asm("v_sin_f32 %0, %1" : "=v"(r) : "v"(f)); return r; }
DEV float cosrev(float f){ float r; asm("v_cos_f32 %0, %1" : "=v"(r) : "v"(f)); return r; }

// problem constants
constexpr int CB = 4, CL = 2048, CE = 1024, CH = 16, CD = 64;
constexpr int CM = CB*CL;           // 8192 rows
constexpr float LOG2E  = 1.44269504088896f;
constexpr float NEGBIG = -1.44269504e9f;    // -1e9 * log2e (exp2 domain)
constexpr float INV2PI = 0.15915494309189535f;

// ---------------- mask dtype detection ----------------
__global__ void detect_mask_kernel(const void* __restrict__ mask, int* __restrict__ flag){
  __shared__ int a_gt1, a_badf, a_oddnz, a_evennz;
  if (threadIdx.x==0){ a_gt1=0; a_badf=0; a_oddnz=0; a_evennz=0; }
  __syncthreads();
  const u32* w = (const u32*)mask;
  int gt1=0, badf=0, oddnz=0, evennz=0;
  for (int i=threadIdx.x; i<2048; i+=256){
    u32 v = w[i];
    if (v > 1u) gt1 = 1;
    if (v != 0u && v != 0x3f800000u) badf = 1;
    if (v != 0u){ if (i & 1) oddnz = 1; else evennz = 1; }
  }
  if (gt1) atomicOr(&a_gt1,1);
  if (badf) atomicOr(&a_badf,1);
  if (oddnz) atomicOr(&a_oddnz,1);
  if (evennz) atomicOr(&a_evennz,1);
  __syncthreads();
  if (threadIdx.x==0){
    int mode;
    if (!a_gt1)           mode = (!a_oddnz && a_evennz) ? 3 : 0;
    else if (!a_badf)     mode = 1;
    else                  mode = 2;
    flag[0] = mode;
  }
}

__global__ void convert_mask_kernel(const void* __restrict__ mask, const int* __restrict__ flag,
                                    float* __restrict__ maskf){
  int i = blockIdx.x*blockDim.x + threadIdx.x;   // B*L
  if (i >= CB*CL) return;
  int mode = flag[0];
  int v;
  if      (mode==0) v = ((const int*)mask)[i] != 0;
  else if (mode==1) v = ((const float*)mask)[i] != 0.f;
  else if (mode==3) v = ((const int*)mask)[2*i] != 0;
  else              v = ((const unsigned char*)mask)[i] != 0;
  maskf[i] = v ? NEGBIG : 0.f;
}

// ---------------- all fp32 -> bf16 casts, one launch ----------------
__global__ void cast_all(const float* __restrict__ q, const float* __restrict__ k,
                         const float* __restrict__ v,
                         const float* __restrict__ wq, const float* __restrict__ wk,
                         const float* __restrict__ wv, const float* __restrict__ wo,
                         u16* __restrict__ oq, u16* __restrict__ ok, u16* __restrict__ ov,
                         u16* __restrict__ owq, u16* __restrict__ owk,
                         u16* __restrict__ owv, u16* __restrict__ owo){
  int i = blockIdx.x*blockDim.x + threadIdx.x;   // 7*2^20 float4 items
  const float* in; u16* out; int j;
  if (i < 3*(1<<21)){
    int w = i >> 21; j = i & ((1<<21)-1);
    in = (w==0)?q:(w==1)?k:v; out = (w==0)?oq:(w==1)?ok:ov;
  } else {
    int r = i - 3*(1<<21);
    int w = r >> 18; j = r & ((1<<18)-1);
    in = (w==0)?wq:(w==1)?wk:(w==2)?wv:wo; out = (w==0)?owq:(w==1)?owk:(w==2)?owv:owo;
  }
  float4 a = ((const float4*)in)[j];
  ushort4 h;
  h.x = f2bf(a.x); h.y = f2bf(a.y); h.z = f2bf(a.z); h.w = f2bf(a.w);
  ((ushort4*)out)[j] = h;
}

// ---------------- QKV projection GEMM (z selects which) ----------------
// 128x128 tile, 4 waves, BK=32, RING-4 counted-vmcnt pipeline (attn_kernel's proven
// ledger applied to GEMM): stage tile t+3 at top of step t, wait vmcnt(8) at the end
// (confirms t+1; {t+2,t+3} = 8 loads stay in flight ~3 steps > HBM latency).
// LDS swizzle for 64B rows: 16B-chunk ^= (row ^ row>>2)&3, both sides -> the b128 read
// (16 rows x 4 chunks per wave) hits all 32 banks exactly once per 8-lane group.
// z=0: Q = qbf@wq^T+bq, scaled 0.125*log2e, RoPE, pack [B,H,L,D]
// z=1: K = kbf@wk^T+bk, RoPE, pack [B,H,L,D]
// z=2: Vt = (wvb@vbf^T)+bv[row], bf16 [E][CM] (pre-transposed V)
__global__ __launch_bounds__(256) void gemm_qkv(
    const u16* __restrict__ qbf, const u16* __restrict__ kbf, const u16* __restrict__ vbf,
    const u16* __restrict__ wqb, const u16* __restrict__ wkb, const u16* __restrict__ wvb,
    const float* __restrict__ bq, const float* __restrict__ bk, const float* __restrict__ bv,
    u16* __restrict__ Qp, u16* __restrict__ Kp, u16* __restrict__ Vt, int zbase)
{
  __shared__ u16 As[4][4096];   // ring of [128 rows][32 k] swizzled tiles (8KB each)
  __shared__ u16 Bs[4][4096];
  const int z = zbase + blockIdx.y;
  const int tid=threadIdx.x, lane=tid&63, wid=tid>>6;
  const int llo=lane&15, lhi=lane>>4;
  const u16* A; const u16* Bt;
  if (z==0){ A=qbf; Bt=wqb; }
  else if (z==1){ A=kbf; Bt=wkb; }
  else { A=wvb; Bt=vbf; }
  // XCD supertile swizzle: each XCD owns an 8x8 block region (4MB working set = L2)
  int bid = blockIdx.x;
  int xcd = bid&7, j = bid>>3;          // j in [0,64)
  int mb, nb;
  if (z<2){ mb = xcd*8 + (j>>3); nb = j&7; }   // Mb=64, Nb=8: supertiles along M
  else    { mb = j>>3; nb = xcd*8 + (j&7); }   // Mb=8, Nb=64: supertiles along N
  const int m0 = mb*128, n0 = nb*128;
  const int wr = wid>>1, wc = wid&1;
  const int rsw2 = (llo ^ (llo>>2)) & 3;       // read-side XOR (matches write swizzle at read rows)

  auto STAGE = [&](int t, int buf){    // 4 gload_lds / thread (A:2, B:2)
    #pragma unroll
    for (int i=0;i<2;i++){
      int c = tid + i*256;              // 0..511 chunks of 16B
      int row = c>>2, ch = c&3;
      int sc = ch ^ ((row ^ (row>>2)) & 3);     // inverse-swizzled source chunk
      __builtin_amdgcn_global_load_lds(GP(A  + (size_t)(m0+row)*CE + t*32 + sc*8),
                                       LP(&As[buf][c*8]), 16, 0, 0);
      __builtin_amdgcn_global_load_lds(GP(Bt + (size_t)(n0+row)*CE + t*32 + sc*8),
                                       LP(&Bs[buf][c*8]), 16, 0, 0);
    }
  };

  f32x4 acc[4][4] = {};

  auto COMP = [&](int t){
    const char* as = (const char*)As[t&3];
    const char* bs = (const char*)Bs[t&3];
    bf16x8 af[4], bf_[4];
    #pragma unroll
    for (int mr=0;mr<4;mr++){
      int r = wr*64+mr*16+llo;
      af[mr] = as_bf(*(const uint4*)(as + r*64 + ((lhi^rsw2)<<4)));
    }
    #pragma unroll
    for (int nr=0;nr<4;nr++){
      int r = wc*64+nr*16+llo;
      bf_[nr] = as_bf(*(const uint4*)(bs + r*64 + ((lhi^rsw2)<<4)));
    }
    #pragma unroll
    for (int mr=0;mr<4;mr++)
      #pragma unroll
      for (int nr=0;nr<4;nr++)
        acc[mr][nr] = __builtin_amdgcn_mfma_f32_16x16x32_bf16(af[mr], bf_[nr], acc[mr][nr], 0,0,0);
  };

  // prologue: 3 tiles in flight (12 loads); wait 8 -> tile 0 landed
  STAGE(0,0); STAGE(1,1); STAGE(2,2);
  WAITB("8");

  // vmcnt ledger (4 loads/tile/thread): entering step t, {t+1,t+2} = 8 outstanding.
  // Top: stage t+3 (-> 12). End: WAITB(8) confirms t+1, leaves {t+2,t+3}.
  // Ring reuse: stage(t+4) at top of t+1 rewrites buf[t&3]; all reads of buf[t&3]
  // completed before the end-of-t barrier, which precedes that issue. Safe.
  #pragma unroll 1
  for (int t=0; t<29; t++){
    STAGE(t+3,(t+3)&3);
    COMP(t);
    WAITB("8");
  }
  COMP(29); WAITB("4");   // {31} stays in flight, 30 confirmed
  COMP(30); WAITB("0");   // 31 confirmed
  COMP(31);               // epilogue touches no LDS -> no trailing barrier

  const int colbase = n0 + wc*64;
  if (z < 2){
    const float* bias = z ? bk : bq;
    u16* outp = z ? Kp : Qp;
    const float scale = z ? 1.f : 0.125f*LOG2E;
    const int h = colbase >> 6;           // wave covers exactly one head
    float b1[2], b2[2], invr[2];
    #pragma unroll
    for (int nr=0;nr<2;nr++){
      int j2 = nr*16 + llo;
      b1[nr] = bias[colbase + j2];
      b2[nr] = bias[colbase + j2 + 32];
      // 10000^{-j2/32} / (2*pi): angle in revolutions per unit l
      invr[nr] = exp2f(-(float)j2 * 0.41524101186092033f) * INV2PI;
    }
    #pragma unroll
    for (int mr=0;mr<4;mr++)
      #pragma unroll
      for (int r=0;r<4;r++){
        int row = m0 + wr*64 + mr*16 + lhi*4 + r;
        int b = row >> 11, l = row & 2047;
        u16* dst = outp + (((size_t)(b*CH + h)*CL + l) << 6);
        #pragma unroll
        for (int nr=0;nr<2;nr++){
          int j2 = nr*16 + llo;
          float x1 = (acc[mr][nr][r]   + b1[nr]) * scale;
          float x2 = (acc[mr][nr+2][r] + b2[nr]) * scale;
          float fr = fractf_((float)l * invr[nr]);
          float sn = sinrev(fr), cs = cosrev(fr);
          dst[j2]      = f2bf(x1*cs - x2*sn);
          dst[j2 + 32] = f2bf(x2*cs + x1*sn);
        }
      }
  } else {
    #pragma unroll
    for (int mr=0;mr<4;mr++)
      #pragma unroll
      for (int r=0;r<4;r++){
        int row = m0 + wr*64 + mr*16 + lhi*4 + r;
        float bvv = bv[row];
        #pragma unroll
        for (int nr=0;nr<4;nr++){
          int col = colbase + nr*16 + llo;
          Vt[(size_t)row*CM + col] = f2bf(acc[mr][nr][r] + bvv);
        }
      }
  }
}

// ---------------- output projection GEMM (fp32 out, bias per col) ----------------
// Same RING-4 BK=32 counted-vmcnt structure as gemm_qkv.
__global__ __launch_bounds__(256) void gemm_out(
    const u16* __restrict__ A, const u16* __restrict__ Bt,
    const float* __restrict__ bias, float* __restrict__ C)
{
  __shared__ u16 As[4][4096];
  __shared__ u16 Bs[4][4096];
  const int tid=threadIdx.x, lane=tid&63, wid=tid>>6;
  const int llo=lane&15, lhi=lane>>4;
  int bid = blockIdx.x;
  int xcd = bid&7, j = bid>>3;
  const int m0 = (xcd*8 + (j>>3))*128, n0 = (j&7)*128;   // Mb=64, Nb=8
  const int wr = wid>>1, wc = wid&1;
  const int rsw2 = (llo ^ (llo>>2)) & 3;

  auto STAGE = [&](int t, int buf){
    #pragma unroll
    for (int i=0;i<2;i++){
      int c = tid + i*256;
      int row = c>>2, ch = c&3;
      int sc = ch ^ ((row ^ (row>>2)) & 3);
      __builtin_amdgcn_global_load_lds(GP(A  + (size_t)(m0+row)*CE + t*32 + sc*8),
                                       LP(&As[buf][c*8]), 16, 0, 0);
      __builtin_amdgcn_global_load_lds(GP(Bt + (size_t)(n0+row)*CE + t*32 + sc*8),
                                       LP(&Bs[buf][c*8]), 16, 0, 0);
    }
  };

  f32x4 acc[4][4] = {};

  auto COMP = [&](int t){
    const char* as = (const char*)As[t&3];
    const char* bs = (const char*)Bs[t&3];
    bf16x8 af[4], bf_[4];
    #pragma unroll
    for (int mr=0;mr<4;mr++){
      int r = wr*64+mr*16+llo;
      af[mr] = as_bf(*(const uint4*)(as + r*64 + ((lhi^rsw2)<<4)));
    }
    #pragma unroll
    for (int nr=0;nr<4;nr++){
      int r = wc*64+nr*16+llo;
      bf_[nr] = as_bf(*(const uint4*)(bs + r*64 + ((lhi^rsw2)<<4)));
    }
    #pragma unroll
    for (int mr=0;mr<4;mr++)
      #pragma unroll
      for (int nr=0;nr<4;nr++)
        acc[mr][nr] = __builtin_amdgcn_mfma_f32_16x16x32_bf16(af[mr], bf_[nr], acc[mr][nr], 0,0,0);
  };

  STAGE(0,0); STAGE(1,1); STAGE(2,2);
  WAITB("8");

  #pragma unroll 1
  for (int t=0; t<29; t++){
    STAGE(t+3,(t+3)&3);
    COMP(t);
    WAITB("8");
  }
  COMP(29); WAITB("4");
  COMP(30); WAITB("0");
  COMP(31);

  #pragma unroll
  for (int mr=0;mr<4;mr++)
    #pragma unroll
    for (int nr=0;nr<4;nr++)
      #pragma unroll
      for (int r=0;r<4;r++){
        int row = m0 + wr*64 + mr*16 + lhi*4 + r;
        int col = n0 + wc*64 + nr*16 + llo;
        C[(size_t)row*CE + col] = acc[mr][nr][r] + bias[col];
      }
}

// ---------------- flash attention, swapped-operand 32x32, counted-vmcnt ring ----------------
// Qp,Kp: [B*H, L, D] bf16 (Q pre-scaled by 0.125*log2e). Vt: [E, CM] bf16. Out AO [B,L,E] bf16.
// grid (64 bh, 8 slot): bid%8 = bh%8 -> one XCD serves 8 bh (K/V L2 reuse).
// Block = q-tiles {15-slot, slot} (uniform 34 KV tiles), 4 waves x 32 q.
// Softmax in exp2 domain; defer-max (THR=12 log2 units, p <= 2^12).
__global__ __launch_bounds__(256,2) void attn_kernel(
    const u16* __restrict__ Qp, const u16* __restrict__ Kp, const u16* __restrict__ Vt,
    const float* __restrict__ maskf, u16* __restrict__ AO)
{
  __shared__ u16 K_lds[4][4096];   // ring of [kv64][d64] swizzled tiles
  __shared__ u16 V_lds[4][4096];   // ring of [d64][kv64] swizzled tiles
  __shared__ float M_lds[2048];    // padding mask row (exp2 domain) for this batch
  const int bh = blockIdx.x;
  const int slot = blockIdx.y;
  const int b = bh >> 4, h = bh & 15;
  const int tid=threadIdx.x, lane=tid&63, wid=tid>>6;
  const int l31 = lane&31, hi = lane>>5;
  const u16* Qh = Qp + (size_t)bh*CL*CD;
  const u16* Kh = Kp + (size_t)bh*CL*CD;
  const u16* Vhd = Vt + (size_t)(h*CD)*CM + b*CL;

  // stage padding-mask row once (8KB). Issued FIRST so the t=0 vmcnt(8) covers it.
  #pragma unroll
  for (int i=0;i<2;i++)
    __builtin_amdgcn_global_load_lds(GP(maskf + b*CL + (i*256+tid)*4),
                                     LP(&M_lds[(i*256+tid)*4]), 16, 0, 0);

  auto STAGE = [&](int t, int buf){   // 4 gload_lds instructions per wave
    const u16* Ksrc = Kh + t*64*CD;
    const u16* Vsrc = Vhd + t*64;
    #pragma unroll
    for (int i=0;i<2;i++){
      int c = tid + i*256;
      int row = c>>3, sc = c&7;
      int c16 = sc ^ (row&7);
      __builtin_amdgcn_global_load_lds(GP(Ksrc + row*CD + c16*8),
                                       LP(&K_lds[buf][c*8]), 16, 0, 0);
      __builtin_amdgcn_global_load_lds(GP(Vsrc + (size_t)row*CM + c16*8),
                                       LP(&V_lds[buf][c*8]), 16, 0, 0);
    }
  };

  const int rowb = l31*128;            // LDS row byte base
  const int rsw  = (l31&7)<<4;
  const int qts2[2] = {15-slot, slot};

  for (int qi=0; qi<2; qi++){
    const int qt = qts2[qi];
    const int qw0 = qt*128 + wid*32;
    const int qlane = qw0 + l31;

    bf16x8 qf[4];
    #pragma unroll
    for (int c=0;c<4;c++)
      qf[c] = as_bf(*(const uint4*)(Qh + (size_t)qlane*CD + c*16 + hi*8));

    f32x16 o0 = {}, o1 = {};
    float m_r = -3e38f, l_r = 0.f;

    const int nt = qt*2 + 2;
    STAGE(0,0); STAGE(1,1);

    for (int t=0; t<nt; t++){
      // vmcnt ledger: entering iter t, {S(t),S(t+1)} = 8 outstanding (each 4/wave)
      if (t+2 < nt){ STAGE(t+2,(t+2)&3); WAITB("8"); }
      else if (t+1 < nt){ WAITB("4"); }
      else { WAITB("0"); }

      const int kv0 = t*64;
      const char* kb = (const char*)K_lds[t&3];
      const char* vb = (const char*)V_lds[t&3];

      // ---- padding mask (broadcast LDS reads; issue early to overlap MFMA)
      f32x4 cm[8];
      #pragma unroll
      for (int s2=0;s2<2;s2++)
        #pragma unroll
        for (int g=0; g<4; g++)
          cm[s2*4+g] = *(const f32x4*)&M_lds[kv0 + s2*32 + g*8 + hi*4];

      // ---- S^T = K @ Q^T  (two 32x32 tiles over kv); Q carries 0.125*log2e
      f32x16 s0 = {}, s1 = {};
      __builtin_amdgcn_s_setprio(1);
      #pragma unroll
      for (int c=0;c<4;c++){
        int cb = (c*32 + hi*16) ^ rsw;
        bf16x8 k0 = as_bf(*(const uint4*)(kb + rowb + cb));
        bf16x8 k1 = as_bf(*(const uint4*)(kb + 4096 + rowb + cb));
        s0 = __builtin_amdgcn_mfma_f32_32x32x16_bf16(k0, qf[c], s0, 0,0,0);
        s1 = __builtin_amdgcn_mfma_f32_32x32x16_bf16(k1, qf[c], s1, 0,0,0);
      }
      __builtin_amdgcn_s_setprio(0);

      // ---- v = s + mask (+ causal on diagonal tiles), in place (exp2 domain)
      if (kv0 + 63 > qw0){
        #pragma unroll
        for (int s2=0;s2<2;s2++){
          f32x16& sv = s2 ? s1 : s0;
          #pragma unroll
          for (int reg=0; reg<16; reg++){
            int k = kv0 + s2*32 + (reg&3) + (reg>>2)*8 + hi*4;
            float v = sv[reg] + cm[s2*4+(reg>>2)][reg&3];
            sv[reg] = (k > qlane) ? v + NEGBIG : v;
          }
        }
      } else {
        #pragma unroll
        for (int s2=0;s2<2;s2++){
          f32x16& sv = s2 ? s1 : s0;
          #pragma unroll
          for (int reg=0; reg<16; reg++)
            sv[reg] = sv[reg] + cm[s2*4+(reg>>2)][reg&3];
        }
      }

      // ---- row max (pairwise + v_max3 tree + partner swap)
      f32x16 mx;
      #pragma unroll
      for (int r=0;r<16;r++) mx[r] = fmaxf(s0[r], s1[r]);
      float a0 = max3f(mx[0],mx[1],mx[2]);
      float a1 = max3f(mx[3],mx[4],mx[5]);
      float a2 = max3f(mx[6],mx[7],mx[8]);
      float a3 = max3f(mx[9],mx[10],mx[11]);
      float a4 = max3f(mx[12],mx[13],mx[14]);
      float vmax = fmaxf(max3f(a0,a1,a2), max3f(a3,a4,mx[15]));
      vmax = fmaxf(vmax, __shfl_xor(vmax, 32));

      // ---- defer-max (T13): rescale only when max grew by > THR (log2 units)
      if (__any(vmax > m_r + 12.0f)){
        float mnew = fmaxf(m_r, vmax);
        float sc = fexp2(m_r - mnew);
        l_r *= sc;
        o0 *= sc; o1 *= sc;
        m_r = mnew;
      }

      // ---- p = exp2(v - m), in place (p <= 2^12)
      #pragma unroll
      for (int r=0;r<16;r++){
        s0[r] = fexp2(s0[r] - m_r);
        s1[r] = fexp2(s1[r] - m_r);
      }
      // ---- row sum
      f32x16 sm = s0 + s1;
      #pragma unroll
      for (int w=8; w>=1; w>>=1)
        #pragma unroll
        for (int r=0;r<w;r++) sm[r] = sm[r] + sm[r+w];
      float rsum = sm[0];
      rsum += __shfl_xor(rsum, 32);
      l_r += rsum;

      // ---- P -> bf16 B-fragments in-register (cvt_pk + permlane32_swap)
      u32 w_[16];
      #pragma unroll
      for (int s2=0;s2<2;s2++){
        f32x16& sv = s2 ? s1 : s0;
        #pragma unroll
        for (int c=0;c<2;c++){
          u32 a  = cvt_pk(sv[c*8+0], sv[c*8+1]);
          u32 bb = cvt_pk(sv[c*8+2], sv[c*8+3]);
          u32 cc = cvt_pk(sv[c*8+4], sv[c*8+5]);
          u32 dd = cvt_pk(sv[c*8+6], sv[c*8+7]);
          plswap(a, cc); plswap(bb, dd);
          int base = (s2*2+c)*4;
          w_[base+0]=a; w_[base+1]=bb; w_[base+2]=cc; w_[base+3]=dd;
        }
      }

      // ---- O^T += V^T @ P^T
      __builtin_amdgcn_s_setprio(1);
      #pragma unroll
      for (int kc=0; kc<4; kc++){
        bf16x8 pf = as_bf(make_uint4(w_[kc*4], w_[kc*4+1], w_[kc*4+2], w_[kc*4+3]));
        int cb = (kc*32 + hi*16) ^ rsw;
        bf16x8 v0 = as_bf(*(const uint4*)(vb + rowb + cb));
        bf16x8 v1 = as_bf(*(const uint4*)(vb + 4096 + rowb + cb));
        o0 = __builtin_amdgcn_mfma_f32_32x32x16_bf16(v0, pf, o0, 0,0,0);
        o1 = __builtin_amdgcn_mfma_f32_32x32x16_bf16(v1, pf, o1, 0,0,0);
      }
      __builtin_amdgcn_s_setprio(0);
      // no trailing barrier: ring depth 4 + per-iter barrier bounds wave skew safely
    }

    // ---- normalize + write O^T: lane has q=qlane, d = mt*32 + g*8 + hi*4 + {0..3}
    float inv = 1.f / l_r;
    u16* dst = AO + (size_t)(b*CL + qlane)*CE + h*CD;
    #pragma unroll
    for (int mt=0; mt<2; mt++){
      f32x16& ov = mt ? o1 : o0;
      #pragma unroll
      for (int g=0; g<4; g++){
        u32 lo  = cvt_pk(ov[g*4+0]*inv, ov[g*4+1]*inv);
        u32 hi2 = cvt_pk(ov[g*4+2]*inv, ov[g*4+3]*inv);
        *(uint2*)(dst + mt*32 + g*8 + hi*4) = make_uint2(lo, hi2);
      }
    }
    // drain + protect ring reuse by qi=1 prologue (and reset vmcnt ledger)
    __syncthreads();
  }
}

// ---------------- launcher ----------------
extern "C" void kernel_launch(void* const* d_in, const int* in_sizes, int n_in,
                              void* d_out, int out_size, void* d_ws, size_t ws_size,
                              hipStream_t stream) {
  const float* query = (const float*)d_in[0];
  const float* key_  = (const float*)d_in[1];
  const float* value = (const float*)d_in[2];
  const float* wq = (const float*)d_in[3];
  const float* bq = (const float*)d_in[4];
  const float* wk = (const float*)d_in[5];
  const float* bk = (const float*)d_in[6];
  const float* wv = (const float*)d_in[7];
  const float* bv = (const float*)d_in[8];
  const float* wo = (const float*)d_in[9];
  const float* bo = (const float*)d_in[10];
  const void*  kpm = d_in[11];

  char* ws = (char*)d_ws;
  constexpr size_t SZ_ME_BF = (size_t)CM*CE*2;    // 16 MiB
  constexpr size_t SZ_EE_BF = (size_t)CE*CE*2;    // 2 MiB
  constexpr size_t OFF_FLAG = 0;
  constexpr size_t OFF_MASKF= 256;
  constexpr size_t OFF_B0   = 65536;              // qbf; later AO
  constexpr size_t OFF_B1   = OFF_B0 + SZ_ME_BF;  // kbf
  constexpr size_t OFF_B2   = OFF_B1 + SZ_ME_BF;  // vbf; later Qp (2-launch path)
  constexpr size_t OFF_WQ   = OFF_B2 + SZ_ME_BF;
  constexpr size_t OFF_WK   = OFF_WQ + SZ_EE_BF;
  constexpr size_t OFF_WV   = OFF_WK + SZ_EE_BF;
  constexpr size_t OFF_WO   = OFF_WV + SZ_EE_BF;
  constexpr size_t OFF_KP   = OFF_WO + SZ_EE_BF;  // Kp
  constexpr size_t OFF_VT   = OFF_KP + SZ_ME_BF;  // Vt [1024][8192]
  constexpr size_t OFF_QP   = OFF_VT + SZ_ME_BF;  // optional dedicated Qp

  int*   flag  = (int*)(ws + OFF_FLAG);
  float* maskf = (float*)(ws + OFF_MASKF);
  u16*  qbf = (u16*)(ws + OFF_B0);
  u16*  kbf = (u16*)(ws + OFF_B1);
  u16*  vbf = (u16*)(ws + OFF_B2);
  u16*  wqb = (u16*)(ws + OFF_WQ);
  u16*  wkb = (u16*)(ws + OFF_WK);
  u16*  wvb = (u16*)(ws + OFF_WV);
  u16*  wob = (u16*)(ws + OFF_WO);
  u16*  Kp  = (u16*)(ws + OFF_KP);
  u16*  Vt  = (u16*)(ws + OFF_VT);
  u16*  AO  = qbf;                   // alias: qbf dead after Q projection

  detect_mask_kernel<<<1,256,0,stream>>>(kpm, flag);
  convert_mask_kernel<<<(CB*CL+255)/256,256,0,stream>>>(kpm, flag, maskf);

  cast_all<<<28672,256,0,stream>>>(query, key_, value, wq, wk, wv, wo,
                                   qbf, kbf, vbf, wqb, wkb, wvb, wob);

  u16* Qp;
  if (ws_size >= OFF_QP + SZ_ME_BF){
    // dedicated Qp buffer: all three projections in one launch (no alias hazard)
    Qp = (u16*)(ws + OFF_QP);
    gemm_qkv<<<dim3(512,3),256,0,stream>>>(qbf, kbf, vbf, wqb, wkb, wvb,
                                           bq, bk, bv, Qp, Kp, Vt, 0);
  } else {
    // fallback: Qp aliases vbf -> V (and K) must complete before Q projection
    Qp = vbf;
    gemm_qkv<<<dim3(512,2),256,0,stream>>>(qbf, kbf, vbf, wqb, wkb, wvb,
                                           bq, bk, bv, Qp, Kp, Vt, 1);
    gemm_qkv<<<dim3(512,1),256,0,stream>>>(qbf, kbf, vbf, wqb, wkb, wvb,
                                           bq, bk, bv, Qp, Kp, Vt, 0);
  }

  attn_kernel<<<dim3(CB*CH, 8),256,0,stream>>>(Qp, Kp, Vt, maskf, AO);

  gemm_out<<<512,256,0,stream>>>(AO, wob, bo, (float*)d_out);
}

// Round 3
// 193.564 us; speedup vs baseline: 1.0955x; 1.0955x over previous
//
#include <hip/hip_runtime.h>

typedef unsigned short u16;
typedef unsigned int   u32;

using bf16x8 = __attribute__((ext_vector_type(8))) __bf16;
using f32x4  = __attribute__((ext_vector_type(4))) float;
using f32x16 = __attribute__((ext_vector_type(16))) float;

#define DEV static __device__ __forceinline__
#define GP(p) (const __attribute__((address_space(1))) void*)(p)
#define LP(p) (__attribute__((address_space(3))) void*)(p)
// fused counted-wait + barrier (T4): memory clobber pins LDS/global ops on both sides
#define WAITB(N) asm volatile("s_waitcnt vmcnt(" N ")\n\ts_barrier" ::: "memory")

DEV u16 f2bf(float f){                      // RNE float->bf16
  u32 u = __builtin_bit_cast(u32, f);
  u32 r = u + 0x7fffu + ((u>>16)&1u);
  return (u16)(r>>16);
}
DEV bf16x8 as_bf(uint4 v){ return __builtin_bit_cast(bf16x8, v); }
DEV u32 cvt_pk(float lo, float hi){
  u32 r;
  asm("v_cvt_pk_bf16_f32 %0, %1, %2" : "=v"(r) : "v"(lo), "v"(hi));
  return r;
}
DEV void plswap(u32 &a, u32 &b){
  auto r = __builtin_amdgcn_permlane32_swap((int)a, (int)b, false, false);
  a = (u32)r[0]; b = (u32)r[1];
}
DEV float fexp2(float x){ float r; asm("v_exp_f32 %0, %1" : "=v"(r) : "v"(x)); return r; }
DEV float max3f(float a, float b, float c){
  float r; asm("v_max3_f32 %0, %1, %2, %3" : "=v"(r) : "v"(a), "v"(b), "v"(c)); return r;
}
// sin/cos of (2*pi*x) via HW revolutions path: fract -> v_sin/v_cos (saves __sincosf's
// radian range-reduction VALU; accuracy ~1e-4 rad, far under bf16 output quantum)
DEV float fractf_(float x){ float r; asm("v_fract_f32 %0, %1" : "=v"(r) : "v"(x)); return r; }
DEV float sinrev(float f){ float r; asm("v_sin_f32 %0, %1" : "=v"(r) : "v"(f)); return r; }
DEV float cosrev(float f){ float r; asm("v_cos_f32 %0, %1" : "=v"(r) : "v"(f)); return r; }

// problem constants
constexpr int CB = 4, CL = 2048, CE = 1024, CH = 16, CD = 64;
constexpr int CM = CB*CL;           // 8192 rows
constexpr float LOG2E  = 1.44269504088896f;
constexpr float NEGBIG = -1.44269504e9f;    // -1e9 * log2e (exp2 domain)
constexpr float INV2PI = 0.15915494309189535f;

// ---------------- mask dtype detection ----------------
__global__ void detect_mask_kernel(const void* __restrict__ mask, int* __restrict__ flag){
  __shared__ int a_gt1, a_badf, a_oddnz, a_evennz;
  if (threadIdx.x==0){ a_gt1=0; a_badf=0; a_oddnz=0; a_evennz=0; }
  __syncthreads();
  const u32* w = (const u32*)mask;
  int gt1=0, badf=0, oddnz=0, evennz=0;
  for (int i=threadIdx.x; i<2048; i+=256){
    u32 v = w[i];
    if (v > 1u) gt1 = 1;
    if (v != 0u && v != 0x3f800000u) badf = 1;
    if (v != 0u){ if (i & 1) oddnz = 1; else evennz = 1; }
  }
  if (gt1) atomicOr(&a_gt1,1);
  if (badf) atomicOr(&a_badf,1);
  if (oddnz) atomicOr(&a_oddnz,1);
  if (evennz) atomicOr(&a_evennz,1);
  __syncthreads();
  if (threadIdx.x==0){
    int mode;
    if (!a_gt1)           mode = (!a_oddnz && a_evennz) ? 3 : 0;
    else if (!a_badf)     mode = 1;
    else                  mode = 2;
    flag[0] = mode;
  }
}

__global__ void convert_mask_kernel(const void* __restrict__ mask, const int* __restrict__ flag,
                                    float* __restrict__ maskf){
  int i = blockIdx.x*blockDim.x + threadIdx.x;   // B*L
  if (i >= CB*CL) return;
  int mode = flag[0];
  int v;
  if      (mode==0) v = ((const int*)mask)[i] != 0;
  else if (mode==1) v = ((const float*)mask)[i] != 0.f;
  else if (mode==3) v = ((const int*)mask)[2*i] != 0;
  else              v = ((const unsigned char*)mask)[i] != 0;
  maskf[i] = v ? NEGBIG : 0.f;
}

// ---------------- all fp32 -> bf16 casts, one launch ----------------
__global__ void cast_all(const float* __restrict__ q, const float* __restrict__ k,
                         const float* __restrict__ v,
                         const float* __restrict__ wq, const float* __restrict__ wk,
                         const float* __restrict__ wv, const float* __restrict__ wo,
                         u16* __restrict__ oq, u16* __restrict__ ok, u16* __restrict__ ov,
                         u16* __restrict__ owq, u16* __restrict__ owk,
                         u16* __restrict__ owv, u16* __restrict__ owo){
  int i = blockIdx.x*blockDim.x + threadIdx.x;   // 7*2^20 float4 items
  const float* in; u16* out; int j;
  if (i < 3*(1<<21)){
    int w = i >> 21; j = i & ((1<<21)-1);
    in = (w==0)?q:(w==1)?k:v; out = (w==0)?oq:(w==1)?ok:ov;
  } else {
    int r = i - 3*(1<<21);
    int w = r >> 18; j = r & ((1<<18)-1);
    in = (w==0)?wq:(w==1)?wk:(w==2)?wv:wo; out = (w==0)?owq:(w==1)?owk:(w==2)?owv:owo;
  }
  float4 a = ((const float4*)in)[j];
  ushort4 h;
  h.x = f2bf(a.x); h.y = f2bf(a.y); h.z = f2bf(a.z); h.w = f2bf(a.w);
  ((ushort4*)out)[j] = h;
}

// ---------------- QKV projection GEMM (z selects which) ----------------
// 256x128 tile, 8 waves, BK=64, RING-3 counted-vmcnt pipeline.
// Geometry/banking are the PROVEN baseline ones (128B LDS rows, 16B-chunk ^= row&7
// both sides -> measured 0 bank conflicts); only the schedule depth changed:
// stage tile t+2 at top of step t (6 gload_lds/thread), WAITB(6) at step end
// confirms tile t+1 (issued ~2 steps = ~900cyc earlier, covers HBM latency);
// 6 loads stay in flight across every barrier (never drain to 0 mid-loop).
// Grid: 256 blocks/z (768 total) at 1 block/CU (144KB LDS) = exactly 3.0 rounds.
// z=0: Q = qbf@wq^T+bq, scaled 0.125*log2e, RoPE, pack [B,H,L,D]
// z=1: K = kbf@wk^T+bk, RoPE, pack [B,H,L,D]
// z=2: Vt = (wvb@vbf^T)+bv[row], bf16 [E][CM] (pre-transposed V)
__global__ __launch_bounds__(512) void gemm_qkv(
    const u16* __restrict__ qbf, const u16* __restrict__ kbf, const u16* __restrict__ vbf,
    const u16* __restrict__ wqb, const u16* __restrict__ wkb, const u16* __restrict__ wvb,
    const float* __restrict__ bq, const float* __restrict__ bk, const float* __restrict__ bv,
    u16* __restrict__ Qp, u16* __restrict__ Kp, u16* __restrict__ Vt, int zbase)
{
  __shared__ u16 As[3][16384];   // ring of [256 rows][64 k] swizzled tiles (32KB)
  __shared__ u16 Bs[3][8192];    // ring of [128 rows][64 k] swizzled tiles (16KB)
  const int z = zbase + blockIdx.y;
  const int tid=threadIdx.x, lane=tid&63, wid=tid>>6;
  const int llo=lane&15, lhi=lane>>4;
  const u16* A; const u16* Bt;
  if (z==0){ A=qbf; Bt=wqb; }
  else if (z==1){ A=kbf; Bt=wkb; }
  else { A=wvb; Bt=vbf; }
  // XCD supertile swizzle: each XCD owns a contiguous block region (L2 reuse)
  int bid = blockIdx.x;                  // [0,256) per z
  int xcd = bid&7, j = bid>>3;           // j in [0,32)
  int mb, nb;
  if (z<2){ mb = xcd*4 + (j>>3); nb = j&7; }     // 32 x 8 tiles of 256x128
  else    { mb = j&3;  nb = xcd*8 + (j>>2); }    // 4 x 64 tiles (M=1024, N=8192)
  const int m0 = mb*256, n0 = nb*128;
  const int wr = wid>>1, wc = wid&1;     // 4M x 2N wave grid, 64x64 per wave
  const int rswA = llo&7;                // read-side XOR (rows within 8-stripe)

  auto STAGE = [&](int t, int buf){      // 6 gload_lds / thread (A:4, B:2)
    #pragma unroll
    for (int i=0;i<4;i++){
      int c = tid + i*512;               // A: 2048 chunks of 16B
      int row = c>>3, ch = c&7;
      int sc = ch ^ (row&7);             // inverse-swizzled source chunk
      __builtin_amdgcn_global_load_lds(GP(A + (size_t)(m0+row)*CE + t*64 + sc*8),
                                       LP(&As[buf][c*8]), 16, 0, 0);
    }
    #pragma unroll
    for (int i=0;i<2;i++){
      int c = tid + i*512;               // B: 1024 chunks of 16B
      int row = c>>3, ch = c&7;
      int sc = ch ^ (row&7);
      __builtin_amdgcn_global_load_lds(GP(Bt + (size_t)(n0+row)*CE + t*64 + sc*8),
                                       LP(&Bs[buf][c*8]), 16, 0, 0);
    }
  };

  f32x4 acc[4][4] = {};

  auto COMP = [&](int buf){
    const char* as = (const char*)As[buf];
    const char* bs = (const char*)Bs[buf];
    #pragma unroll
    for (int ks=0; ks<2; ks++){
      bf16x8 af[4], bf_[4];
      #pragma unroll
      for (int mr=0;mr<4;mr++){
        int r = wr*64+mr*16+llo;
        af[mr] = as_bf(*(const uint4*)(as + r*128 + (((ks*4+lhi)^rswA)<<4)));
      }
      #pragma unroll
      for (int nr=0;nr<4;nr++){
        int r = wc*64+nr*16+llo;
        bf_[nr] = as_bf(*(const uint4*)(bs + r*128 + (((ks*4+lhi)^rswA)<<4)));
      }
      #pragma unroll
      for (int mr=0;mr<4;mr++)
        #pragma unroll
        for (int nr=0;nr<4;nr++)
          acc[mr][nr] = __builtin_amdgcn_mfma_f32_16x16x32_bf16(af[mr], bf_[nr], acc[mr][nr], 0,0,0);
    }
  };

  // prologue: tiles 0,1 in flight (12 loads); wait 6 -> tile 0 landed
  STAGE(0,0); STAGE(1,1);
  WAITB("6");

  // Ring reuse: STAGE(t+2) rewrites buf[(t+2)%3] = buf[(t-1)%3], whose last reads
  // (COMP(t-1)) completed before the end-of-(t-1) barrier preceding this issue.
  #pragma unroll 1
  for (int t=0; t<14; t++){
    STAGE(t+2, (t+2)%3);
    COMP(t%3);
    WAITB("6");                          // tile t+1 landed; t+2 (6 loads) in flight
  }
  COMP(2); WAITB("0");                   // t=14 (buf 2); drain tile 15
  COMP(0);                               // t=15 (buf 0); epilogue touches no LDS

  const int colbase = n0 + wc*64;
  if (z < 2){
    const float* bias = z ? bk : bq;
    u16* outp = z ? Kp : Qp;
    const float scale = z ? 1.f : 0.125f*LOG2E;
    const int h = colbase >> 6;           // wave covers exactly one head
    float b1[2], b2[2], invr[2];
    #pragma unroll
    for (int nr=0;nr<2;nr++){
      int j2 = nr*16 + llo;
      b1[nr] = bias[colbase + j2];
      b2[nr] = bias[colbase + j2 + 32];
      // 10000^{-j2/32} / (2*pi): angle in revolutions per unit l
      invr[nr] = exp2f(-(float)j2 * 0.41524101186092033f) * INV2PI;
    }
    #pragma unroll
    for (int mr=0;mr<4;mr++)
      #pragma unroll
      for (int r=0;r<4;r++){
        int row = m0 + wr*64 + mr*16 + lhi*4 + r;
        int b = row >> 11, l = row & 2047;
        u16* dst = outp + (((size_t)(b*CH + h)*CL + l) << 6);
        #pragma unroll
        for (int nr=0;nr<2;nr++){
          int j2 = nr*16 + llo;
          float x1 = (acc[mr][nr][r]   + b1[nr]) * scale;
          float x2 = (acc[mr][nr+2][r] + b2[nr]) * scale;
          float fr = fractf_((float)l * invr[nr]);
          float sn = sinrev(fr), cs = cosrev(fr);
          dst[j2]      = f2bf(x1*cs - x2*sn);
          dst[j2 + 32] = f2bf(x2*cs + x1*sn);
        }
      }
  } else {
    #pragma unroll
    for (int mr=0;mr<4;mr++)
      #pragma unroll
      for (int r=0;r<4;r++){
        int row = m0 + wr*64 + mr*16 + lhi*4 + r;
        float bvv = bv[row];
        #pragma unroll
        for (int nr=0;nr<4;nr++){
          int col = colbase + nr*16 + llo;
          Vt[(size_t)row*CM + col] = f2bf(acc[mr][nr][r] + bvv);
        }
      }
  }
}

// ---------------- output projection GEMM (fp32 out, bias per col) ----------------
// Same 256x128 / 8-wave / ring-3 counted-vmcnt structure as gemm_qkv.
__global__ __launch_bounds__(512) void gemm_out(
    const u16* __restrict__ A, const u16* __restrict__ Bt,
    const float* __restrict__ bias, float* __restrict__ C)
{
  __shared__ u16 As[3][16384];
  __shared__ u16 Bs[3][8192];
  const int tid=threadIdx.x, lane=tid&63, wid=tid>>6;
  const int llo=lane&15, lhi=lane>>4;
  int bid = blockIdx.x;
  int xcd = bid&7, j = bid>>3;
  const int m0 = (xcd*4 + (j>>3))*256, n0 = (j&7)*128;   // 32 x 8 tiles
  const int wr = wid>>1, wc = wid&1;
  const int rswA = llo&7;

  auto STAGE = [&](int t, int buf){
    #pragma unroll
    for (int i=0;i<4;i++){
      int c = tid + i*512;
      int row = c>>3, ch = c&7;
      int sc = ch ^ (row&7);
      __builtin_amdgcn_global_load_lds(GP(A + (size_t)(m0+row)*CE + t*64 + sc*8),
                                       LP(&As[buf][c*8]), 16, 0, 0);
    }
    #pragma unroll
    for (int i=0;i<2;i++){
      int c = tid + i*512;
      int row = c>>3, ch = c&7;
      int sc = ch ^ (row&7);
      __builtin_amdgcn_global_load_lds(GP(Bt + (size_t)(n0+row)*CE + t*64 + sc*8),
                                       LP(&Bs[buf][c*8]), 16, 0, 0);
    }
  };

  f32x4 acc[4][4] = {};

  auto COMP = [&](int buf){
    const char* as = (const char*)As[buf];
    const char* bs = (const char*)Bs[buf];
    #pragma unroll
    for (int ks=0; ks<2; ks++){
      bf16x8 af[4], bf_[4];
      #pragma unroll
      for (int mr=0;mr<4;mr++){
        int r = wr*64+mr*16+llo;
        af[mr] = as_bf(*(const uint4*)(as + r*128 + (((ks*4+lhi)^rswA)<<4)));
      }
      #pragma unroll
      for (int nr=0;nr<4;nr++){
        int r = wc*64+nr*16+llo;
        bf_[nr] = as_bf(*(const uint4*)(bs + r*128 + (((ks*4+lhi)^rswA)<<4)));
      }
      #pragma unroll
      for (int mr=0;mr<4;mr++)
        #pragma unroll
        for (int nr=0;nr<4;nr++)
          acc[mr][nr] = __builtin_amdgcn_mfma_f32_16x16x32_bf16(af[mr], bf_[nr], acc[mr][nr], 0,0,0);
    }
  };

  STAGE(0,0); STAGE(1,1);
  WAITB("6");

  #pragma unroll 1
  for (int t=0; t<14; t++){
    STAGE(t+2, (t+2)%3);
    COMP(t%3);
    WAITB("6");
  }
  COMP(2); WAITB("0");
  COMP(0);

  #pragma unroll
  for (int mr=0;mr<4;mr++)
    #pragma unroll
    for (int nr=0;nr<4;nr++)
      #pragma unroll
      for (int r=0;r<4;r++){
        int row = m0 + wr*64 + mr*16 + lhi*4 + r;
        int col = n0 + wc*64 + nr*16 + llo;
        C[(size_t)row*CE + col] = acc[mr][nr][r] + bias[col];
      }
}

// ---------------- flash attention, swapped-operand 32x32, counted-vmcnt ring ----------------
// Qp,Kp: [B*H, L, D] bf16 (Q pre-scaled by 0.125*log2e). Vt: [E, CM] bf16. Out AO [B,L,E] bf16.
// grid (64 bh, 8 slot): bid%8 = bh%8 -> one XCD serves 8 bh (K/V L2 reuse).
// Block = q-tiles {15-slot, slot} (uniform 34 KV tiles), 4 waves x 32 q.
// Softmax in exp2 domain; defer-max (THR=12 log2 units, p <= 2^12).
__global__ __launch_bounds__(256,2) void attn_kernel(
    const u16* __restrict__ Qp, const u16* __restrict__ Kp, const u16* __restrict__ Vt,
    const float* __restrict__ maskf, u16* __restrict__ AO)
{
  __shared__ u16 K_lds[4][4096];   // ring of [kv64][d64] swizzled tiles
  __shared__ u16 V_lds[4][4096];   // ring of [d64][kv64] swizzled tiles
  __shared__ float M_lds[2048];    // padding mask row (exp2 domain) for this batch
  const int bh = blockIdx.x;
  const int slot = blockIdx.y;
  const int b = bh >> 4, h = bh & 15;
  const int tid=threadIdx.x, lane=tid&63, wid=tid>>6;
  const int l31 = lane&31, hi = lane>>5;
  const u16* Qh = Qp + (size_t)bh*CL*CD;
  const u16* Kh = Kp + (size_t)bh*CL*CD;
  const u16* Vhd = Vt + (size_t)(h*CD)*CM + b*CL;

  // stage padding-mask row once (8KB). Issued FIRST so the t=0 vmcnt(8) covers it.
  #pragma unroll
  for (int i=0;i<2;i++)
    __builtin_amdgcn_global_load_lds(GP(maskf + b*CL + (i*256+tid)*4),
                                     LP(&M_lds[(i*256+tid)*4]), 16, 0, 0);

  auto STAGE = [&](int t, int buf){   // 4 gload_lds instructions per wave
    const u16* Ksrc = Kh + t*64*CD;
    const u16* Vsrc = Vhd + t*64;
    #pragma unroll
    for (int i=0;i<2;i++){
      int c = tid + i*256;
      int row = c>>3, sc = c&7;
      int c16 = sc ^ (row&7);
      __builtin_amdgcn_global_load_lds(GP(Ksrc + row*CD + c16*8),
                                       LP(&K_lds[buf][c*8]), 16, 0, 0);
      __builtin_amdgcn_global_load_lds(GP(Vsrc + (size_t)row*CM + c16*8),
                                       LP(&V_lds[buf][c*8]), 16, 0, 0);
    }
  };

  const int rowb = l31*128;            // LDS row byte base
  const int rsw  = (l31&7)<<4;
  const int qts2[2] = {15-slot, slot};

  for (int qi=0; qi<2; qi++){
    const int qt = qts2[qi];
    const int qw0 = qt*128 + wid*32;
    const int qlane = qw0 + l31;

    bf16x8 qf[4];
    #pragma unroll
    for (int c=0;c<4;c++)
      qf[c] = as_bf(*(const uint4*)(Qh + (size_t)qlane*CD + c*16 + hi*8));

    f32x16 o0 = {}, o1 = {};
    float m_r = -3e38f, l_r = 0.f;

    const int nt = qt*2 + 2;
    STAGE(0,0); STAGE(1,1);

    for (int t=0; t<nt; t++){
      // vmcnt ledger: entering iter t, {S(t),S(t+1)} = 8 outstanding (each 4/wave)
      if (t+2 < nt){ STAGE(t+2,(t+2)&3); WAITB("8"); }
      else if (t+1 < nt){ WAITB("4"); }
      else { WAITB("0"); }

      const int kv0 = t*64;
      const char* kb = (const char*)K_lds[t&3];
      const char* vb = (const char*)V_lds[t&3];

      // ---- padding mask (broadcast LDS reads; issue early to overlap MFMA)
      f32x4 cm[8];
      #pragma unroll
      for (int s2=0;s2<2;s2++)
        #pragma unroll
        for (int g=0; g<4; g++)
          cm[s2*4+g] = *(const f32x4*)&M_lds[kv0 + s2*32 + g*8 + hi*4];

      // ---- S^T = K @ Q^T  (two 32x32 tiles over kv); Q carries 0.125*log2e
      f32x16 s0 = {}, s1 = {};
      __builtin_amdgcn_s_setprio(1);
      #pragma unroll
      for (int c=0;c<4;c++){
        int cb = (c*32 + hi*16) ^ rsw;
        bf16x8 k0 = as_bf(*(const uint4*)(kb + rowb + cb));
        bf16x8 k1 = as_bf(*(const uint4*)(kb + 4096 + rowb + cb));
        s0 = __builtin_amdgcn_mfma_f32_32x32x16_bf16(k0, qf[c], s0, 0,0,0);
        s1 = __builtin_amdgcn_mfma_f32_32x32x16_bf16(k1, qf[c], s1, 0,0,0);
      }
      __builtin_amdgcn_s_setprio(0);

      // ---- v = s + mask (+ causal on diagonal tiles), in place (exp2 domain)
      if (kv0 + 63 > qw0){
        #pragma unroll
        for (int s2=0;s2<2;s2++){
          f32x16& sv = s2 ? s1 : s0;
          #pragma unroll
          for (int reg=0; reg<16; reg++){
            int k = kv0 + s2*32 + (reg&3) + (reg>>2)*8 + hi*4;
            float v = sv[reg] + cm[s2*4+(reg>>2)][reg&3];
            sv[reg] = (k > qlane) ? v + NEGBIG : v;
          }
        }
      } else {
        #pragma unroll
        for (int s2=0;s2<2;s2++){
          f32x16& sv = s2 ? s1 : s0;
          #pragma unroll
          for (int reg=0; reg<16; reg++)
            sv[reg] = sv[reg] + cm[s2*4+(reg>>2)][reg&3];
        }
      }

      // ---- row max (pairwise + v_max3 tree + partner swap)
      f32x16 mx;
      #pragma unroll
      for (int r=0;r<16;r++) mx[r] = fmaxf(s0[r], s1[r]);
      float a0 = max3f(mx[0],mx[1],mx[2]);
      float a1 = max3f(mx[3],mx[4],mx[5]);
      float a2 = max3f(mx[6],mx[7],mx[8]);
      float a3 = max3f(mx[9],mx[10],mx[11]);
      float a4 = max3f(mx[12],mx[13],mx[14]);
      float vmax = fmaxf(max3f(a0,a1,a2), max3f(a3,a4,mx[15]));
      vmax = fmaxf(vmax, __shfl_xor(vmax, 32));

      // ---- defer-max (T13): rescale only when max grew by > THR (log2 units)
      if (__any(vmax > m_r + 12.0f)){
        float mnew = fmaxf(m_r, vmax);
        float sc = fexp2(m_r - mnew);
        l_r *= sc;
        o0 *= sc; o1 *= sc;
        m_r = mnew;
      }

      // ---- p = exp2(v - m), in place (p <= 2^12)
      #pragma unroll
      for (int r=0;r<16;r++){
        s0[r] = fexp2(s0[r] - m_r);
        s1[r] = fexp2(s1[r] - m_r);
      }
      // ---- row sum
      f32x16 sm = s0 + s1;
      #pragma unroll
      for (int w=8; w>=1; w>>=1)
        #pragma unroll
        for (int r=0;r<w;r++) sm[r] = sm[r] + sm[r+w];
      float rsum = sm[0];
      rsum += __shfl_xor(rsum, 32);
      l_r += rsum;

      // ---- P -> bf16 B-fragments in-register (cvt_pk + permlane32_swap)
      u32 w_[16];
      #pragma unroll
      for (int s2=0;s2<2;s2++){
        f32x16& sv = s2 ? s1 : s0;
        #pragma unroll
        for (int c=0;c<2;c++){
          u32 a  = cvt_pk(sv[c*8+0], sv[c*8+1]);
          u32 bb = cvt_pk(sv[c*8+2], sv[c*8+3]);
          u32 cc = cvt_pk(sv[c*8+4], sv[c*8+5]);
          u32 dd = cvt_pk(sv[c*8+6], sv[c*8+7]);
          plswap(a, cc); plswap(bb, dd);
          int base = (s2*2+c)*4;
          w_[base+0]=a; w_[base+1]=bb; w_[base+2]=cc; w_[base+3]=dd;
        }
      }

      // ---- O^T += V^T @ P^T
      __builtin_amdgcn_s_setprio(1);
      #pragma unroll
      for (int kc=0; kc<4; kc++){
        bf16x8 pf = as_bf(make_uint4(w_[kc*4], w_[kc*4+1], w_[kc*4+2], w_[kc*4+3]));
        int cb = (kc*32 + hi*16) ^ rsw;
        bf16x8 v0 = as_bf(*(const uint4*)(vb + rowb + cb));
        bf16x8 v1 = as_bf(*(const uint4*)(vb + 4096 + rowb + cb));
        o0 = __builtin_amdgcn_mfma_f32_32x32x16_bf16(v0, pf, o0, 0,0,0);
        o1 = __builtin_amdgcn_mfma_f32_32x32x16_bf16(v1, pf, o1, 0,0,0);
      }
      __builtin_amdgcn_s_setprio(0);
      // no trailing barrier: ring depth 4 + per-iter barrier bounds wave skew safely
    }

    // ---- normalize + write O^T: lane has q=qlane, d = mt*32 + g*8 + hi*4 + {0..3}
    float inv = 1.f / l_r;
    u16* dst = AO + (size_t)(b*CL + qlane)*CE + h*CD;
    #pragma unroll
    for (int mt=0; mt<2; mt++){
      f32x16& ov = mt ? o1 : o0;
      #pragma unroll
      for (int g=0; g<4; g++){
        u32 lo  = cvt_pk(ov[g*4+0]*inv, ov[g*4+1]*inv);
        u32 hi2 = cvt_pk(ov[g*4+2]*inv, ov[g*4+3]*inv);
        *(uint2*)(dst + mt*32 + g*8 + hi*4) = make_uint2(lo, hi2);
      }
    }
    // drain + protect ring reuse by qi=1 prologue (and reset vmcnt ledger)
    __syncthreads();
  }
}

// ---------------- launcher ----------------
extern "C" void kernel_launch(void* const* d_in, const int* in_sizes, int n_in,
                              void* d_out, int out_size, void* d_ws, size_t ws_size,
                              hipStream_t stream) {
  const float* query = (const float*)d_in[0];
  const float* key_  = (const float*)d_in[1];
  const float* value = (const float*)d_in[2];
  const float* wq = (const float*)d_in[3];
  const float* bq = (const float*)d_in[4];
  const float* wk = (const float*)d_in[5];
  const float* bk = (const float*)d_in[6];
  const float* wv = (const float*)d_in[7];
  const float* bv = (const float*)d_in[8];
  const float* wo = (const float*)d_in[9];
  const float* bo = (const float*)d_in[10];
  const void*  kpm = d_in[11];

  char* ws = (char*)d_ws;
  constexpr size_t SZ_ME_BF = (size_t)CM*CE*2;    // 16 MiB
  constexpr size_t SZ_EE_BF = (size_t)CE*CE*2;    // 2 MiB
  constexpr size_t OFF_FLAG = 0;
  constexpr size_t OFF_MASKF= 256;
  constexpr size_t OFF_B0   = 65536;              // qbf; later AO
  constexpr size_t OFF_B1   = OFF_B0 + SZ_ME_BF;  // kbf
  constexpr size_t OFF_B2   = OFF_B1 + SZ_ME_BF;  // vbf; later Qp (2-launch path)
  constexpr size_t OFF_WQ   = OFF_B2 + SZ_ME_BF;
  constexpr size_t OFF_WK   = OFF_WQ + SZ_EE_BF;
  constexpr size_t OFF_WV   = OFF_WK + SZ_EE_BF;
  constexpr size_t OFF_WO   = OFF_WV + SZ_EE_BF;
  constexpr size_t OFF_KP   = OFF_WO + SZ_EE_BF;  // Kp
  constexpr size_t OFF_VT   = OFF_KP + SZ_ME_BF;  // Vt [1024][8192]
  constexpr size_t OFF_QP   = OFF_VT + SZ_ME_BF;  // optional dedicated Qp

  int*   flag  = (int*)(ws + OFF_FLAG);
  float* maskf = (float*)(ws + OFF_MASKF);
  u16*  qbf = (u16*)(ws + OFF_B0);
  u16*  kbf = (u16*)(ws + OFF_B1);
  u16*  vbf = (u16*)(ws + OFF_B2);
  u16*  wqb = (u16*)(ws + OFF_WQ);
  u16*  wkb = (u16*)(ws + OFF_WK);
  u16*  wvb = (u16*)(ws + OFF_WV);
  u16*  wob = (u16*)(ws + OFF_WO);
  u16*  Kp  = (u16*)(ws + OFF_KP);
  u16*  Vt  = (u16*)(ws + OFF_VT);
  u16*  AO  = qbf;                   // alias: qbf dead after Q projection

  detect_mask_kernel<<<1,256,0,stream>>>(kpm, flag);
  convert_mask_kernel<<<(CB*CL+255)/256,256,0,stream>>>(kpm, flag, maskf);

  cast_all<<<28672,256,0,stream>>>(query, key_, value, wq, wk, wv, wo,
                                   qbf, kbf, vbf, wqb, wkb, wvb, wob);

  u16* Qp;
  if (ws_size >= OFF_QP + SZ_ME_BF){
    // dedicated Qp buffer: all three projections in one launch (no alias hazard)
    Qp = (u16*)(ws + OFF_QP);
    gemm_qkv<<<dim3(256,3),512,0,stream>>>(qbf, kbf, vbf, wqb, wkb, wvb,
                                           bq, bk, bv, Qp, Kp, Vt, 0);
  } else {
    // fallback: Qp aliases vbf -> V (and K) must complete before Q projection
    Qp = vbf;
    gemm_qkv<<<dim3(256,2),512,0,stream>>>(qbf, kbf, vbf, wqb, wkb, wvb,
                                           bq, bk, bv, Qp, Kp, Vt, 1);
    gemm_qkv<<<dim3(256,1),512,0,stream>>>(qbf, kbf, vbf, wqb, wkb, wvb,
                                           bq, bk, bv, Qp, Kp, Vt, 0);
  }

  attn_kernel<<<dim3(CB*CH, 8),256,0,stream>>>(Qp, Kp, Vt, maskf, AO);

  gemm_out<<<256,512,0,stream>>>(AO, wob, bo, (float*)d_out);
}

// Round 4
// 190.930 us; speedup vs baseline: 1.1106x; 1.0138x over previous
//
#include <hip/hip_runtime.h>

typedef unsigned short u16;
typedef unsigned int   u32;

using bf16x8 = __attribute__((ext_vector_type(8))) __bf16;
using f32x4  = __attribute__((ext_vector_type(4))) float;
using f32x16 = __attribute__((ext_vector_type(16))) float;
using u32x4  = __attribute__((ext_vector_type(4))) u32;

#define DEV static __device__ __forceinline__
#define GP(p) (const __attribute__((address_space(1))) void*)(p)
#define LP(p) (__attribute__((address_space(3))) void*)(p)
// fused counted-wait + barrier (T4)
#define WAITB(N) asm volatile("s_waitcnt vmcnt(" N ")\n\ts_barrier" ::: "memory")
// counted VMEM wait for reg-staged loads; sched_barrier pins register-only consumers (rule #18)
#define WAITVM(N) do{ asm volatile("s_waitcnt vmcnt(" N ")" ::: "memory"); \
                      __builtin_amdgcn_sched_barrier(0); }while(0)
// end-of-step: drain LDS ops then barrier
#define LGKMB asm volatile("s_waitcnt lgkmcnt(0)\n\ts_barrier" ::: "memory")

DEV u16 f2bf(float f){                      // RNE float->bf16
  u32 u = __builtin_bit_cast(u32, f);
  u32 r = u + 0x7fffu + ((u>>16)&1u);
  return (u16)(r>>16);
}
DEV float bcf(u32 x){ return __builtin_bit_cast(float, x); }
DEV bf16x8 as_bf(uint4 v){ return __builtin_bit_cast(bf16x8, v); }
DEV u32 cvt_pk(float lo, float hi){
  u32 r;
  asm("v_cvt_pk_bf16_f32 %0, %1, %2" : "=v"(r) : "v"(lo), "v"(hi));
  return r;
}
DEV void plswap(u32 &a, u32 &b){
  auto r = __builtin_amdgcn_permlane32_swap((int)a, (int)b, false, false);
  a = (u32)r[0]; b = (u32)r[1];
}
DEV float fexp2(float x){ float r; asm("v_exp_f32 %0, %1" : "=v"(r) : "v"(x)); return r; }
DEV float max3f(float a, float b, float c){
  float r; asm("v_max3_f32 %0, %1, %2, %3" : "=v"(r) : "v"(a), "v"(b), "v"(c)); return r;
}
DEV float fractf_(float x){ float r; asm("v_fract_f32 %0, %1" : "=v"(r) : "v"(x)); return r; }
DEV float sinrev(float f){ float r; asm("v_sin_f32 %0, %1" : "=v"(r) : "v"(f)); return r; }
DEV float cosrev(float f){ float r; asm("v_cos_f32 %0, %1" : "=v"(r) : "v"(f)); return r; }

// problem constants
constexpr int CB = 4, CL = 2048, CE = 1024, CH = 16, CD = 64;
constexpr int CM = CB*CL;           // 8192 rows
constexpr float LOG2E  = 1.44269504088896f;
constexpr float NEGBIG = -1.44269504e9f;    // -1e9 * log2e (exp2 domain)
constexpr float INV2PI = 0.15915494309189535f;

// ---------------- mask dtype detection ----------------
__global__ void detect_mask_kernel(const void* __restrict__ mask, int* __restrict__ flag){
  __shared__ int a_gt1, a_badf, a_oddnz, a_evennz;
  if (threadIdx.x==0){ a_gt1=0; a_badf=0; a_oddnz=0; a_evennz=0; }
  __syncthreads();
  const u32* w = (const u32*)mask;
  int gt1=0, badf=0, oddnz=0, evennz=0;
  for (int i=threadIdx.x; i<2048; i+=256){
    u32 v = w[i];
    if (v > 1u) gt1 = 1;
    if (v != 0u && v != 0x3f800000u) badf = 1;
    if (v != 0u){ if (i & 1) oddnz = 1; else evennz = 1; }
  }
  if (gt1) atomicOr(&a_gt1,1);
  if (badf) atomicOr(&a_badf,1);
  if (oddnz) atomicOr(&a_oddnz,1);
  if (evennz) atomicOr(&a_evennz,1);
  __syncthreads();
  if (threadIdx.x==0){
    int mode;
    if (!a_gt1)           mode = (!a_oddnz && a_evennz) ? 3 : 0;
    else if (!a_badf)     mode = 1;
    else                  mode = 2;
    flag[0] = mode;
  }
}

__global__ void convert_mask_kernel(const void* __restrict__ mask, const int* __restrict__ flag,
                                    float* __restrict__ maskf){
  int i = blockIdx.x*blockDim.x + threadIdx.x;   // B*L
  if (i >= CB*CL) return;
  int mode = flag[0];
  int v;
  if      (mode==0) v = ((const int*)mask)[i] != 0;
  else if (mode==1) v = ((const float*)mask)[i] != 0.f;
  else if (mode==3) v = ((const int*)mask)[2*i] != 0;
  else              v = ((const unsigned char*)mask)[i] != 0;
  maskf[i] = v ? NEGBIG : 0.f;
}

// ---------------- QKV projection GEMM, fp32 sources, fused cast-in-staging ----------------
// 256x128 tile, 8 waves, BK=64, ring-2 LDS + depth-1 reg pipeline (T14 async split):
//   step t: issue asm global_load_dwordx4 for tile t+2 into reg set[t&1] (12 loads),
//           vmcnt(12) -> tile t+1 regs landed (issued one full step earlier),
//           cvt_pk -> ds_write tile t+1 into buf[(t+1)&1],
//           COMP(t) from buf[t&1], lgkmcnt(0)+barrier.
// LDS layout/banking identical to the proven baseline (128B rows, chunk ^= row&7,
// measured 0 conflicts). LDS write bytes unchanged vs global_load_lds path.
// This removes the separate cast_all pass entirely (-27us of HBM-bound timeline).
// z=0: Q = query@wq^T+bq, scaled 0.125*log2e, RoPE, pack [B,H,L,D]
// z=1: K = key@wk^T+bk, RoPE, pack [B,H,L,D]
// z=2: Vt = (wv@value^T)+bv[row], bf16 [E][CM] (pre-transposed V)
__global__ __launch_bounds__(512) void gemm_qkv(
    const float* __restrict__ query, const float* __restrict__ keyp,
    const float* __restrict__ value,
    const float* __restrict__ wq, const float* __restrict__ wk,
    const float* __restrict__ wv,
    const float* __restrict__ bq, const float* __restrict__ bk, const float* __restrict__ bv,
    u16* __restrict__ Qp, u16* __restrict__ Kp, u16* __restrict__ Vt)
{
  __shared__ u16 As[2][16384];   // [buf][256 rows][64 k] swizzled (32KB each)
  __shared__ u16 Bs[2][8192];    // [buf][128 rows][64 k] swizzled (16KB each)
  const int z = blockIdx.y;
  const int tid=threadIdx.x, lane=tid&63, wid=tid>>6;
  const int llo=lane&15, lhi=lane>>4;
  const float* Af; const float* Btf;
  if (z==0){ Af=query; Btf=wq; }
  else if (z==1){ Af=keyp; Btf=wk; }
  else { Af=wv; Btf=value; }
  int bid = blockIdx.x;                  // [0,256) per z
  int xcd = bid&7, j = bid>>3;           // j in [0,32)
  int mb, nb;
  if (z<2){ mb = xcd*4 + (j>>3); nb = j&7; }     // 32 x 8 tiles of 256x128
  else    { mb = j&3;  nb = xcd*8 + (j>>2); }    // 4 x 64 tiles (M=1024, N=8192)
  const int m0 = mb*256, n0 = nb*128;
  const int wr = wid>>1, wc = wid&1;     // 4M x 2N wave grid, 64x64 per wave
  const int rswA = llo&7;

  // per-thread staging chunk addresses (source pre-inverse-swizzled; LDS linear)
  const float* aptr[4]; int aco[4];
  #pragma unroll
  for (int i=0;i<4;i++){
    int c = tid + i*512, row=c>>3, sc=(c&7)^(row&7);
    aptr[i] = Af + (size_t)(m0+row)*CE + sc*8;
    aco[i] = c*8;
  }
  const float* bptr[2]; int bco[2];
  #pragma unroll
  for (int i=0;i<2;i++){
    int c = tid + i*512, row=c>>3, sc=(c&7)^(row&7);
    bptr[i] = Btf + (size_t)(n0+row)*CE + sc*8;
    bco[i] = c*8;
  }

  u32x4 A0[8], B0[4], A1[8], B1[4];      // double reg sets (tile parity)

#define LOADT(T, RA, RB) do{ \
  _Pragma("unroll") \
  for (int i=0;i<4;i++){ \
    asm volatile("global_load_dwordx4 %0, %2, off\n\tglobal_load_dwordx4 %1, %2, off offset:16" \
      : "=&v"(RA[2*i]), "=&v"(RA[2*i+1]) : "v"(aptr[i] + (size_t)(T)*64) : "memory"); \
  } \
  _Pragma("unroll") \
  for (int i=0;i<2;i++){ \
    asm volatile("global_load_dwordx4 %0, %2, off\n\tglobal_load_dwordx4 %1, %2, off offset:16" \
      : "=&v"(RB[2*i]), "=&v"(RB[2*i+1]) : "v"(bptr[i] + (size_t)(T)*64) : "memory"); \
  } \
}while(0)

#define CVTW(dst, lo4, hi4) do{ \
  dst.x = cvt_pk(bcf(lo4.x), bcf(lo4.y)); \
  dst.y = cvt_pk(bcf(lo4.z), bcf(lo4.w)); \
  dst.z = cvt_pk(bcf(hi4.x), bcf(hi4.y)); \
  dst.w = cvt_pk(bcf(hi4.z), bcf(hi4.w)); \
}while(0)

#define WRITET(BUF, RA, RB) do{ \
  _Pragma("unroll") \
  for (int i=0;i<4;i++){ \
    u32x4 w; CVTW(w, RA[2*i], RA[2*i+1]); \
    *(u32x4*)&As[BUF][aco[i]] = w; \
  } \
  _Pragma("unroll") \
  for (int i=0;i<2;i++){ \
    u32x4 w; CVTW(w, RB[2*i], RB[2*i+1]); \
    *(u32x4*)&Bs[BUF][bco[i]] = w; \
  } \
}while(0)

  f32x4 acc[4][4] = {};

  auto COMP = [&](int buf){
    const char* as = (const char*)As[buf];
    const char* bs = (const char*)Bs[buf];
    #pragma unroll
    for (int ks=0; ks<2; ks++){
      bf16x8 af[4], bf_[4];
      #pragma unroll
      for (int mr=0;mr<4;mr++){
        int r = wr*64+mr*16+llo;
        af[mr] = as_bf(*(const uint4*)(as + r*128 + (((ks*4+lhi)^rswA)<<4)));
      }
      #pragma unroll
      for (int nr=0;nr<4;nr++){
        int r = wc*64+nr*16+llo;
        bf_[nr] = as_bf(*(const uint4*)(bs + r*128 + (((ks*4+lhi)^rswA)<<4)));
      }
      #pragma unroll
      for (int mr=0;mr<4;mr++)
        #pragma unroll
        for (int nr=0;nr<4;nr++)
          acc[mr][nr] = __builtin_amdgcn_mfma_f32_16x16x32_bf16(af[mr], bf_[nr], acc[mr][nr], 0,0,0);
    }
  };

  // prologue: tiles 0,1 loads in flight; tile0 regs -> LDS buf0
  LOADT(0, A0, B0);
  LOADT(1, A1, B1);
  WAITVM("12");
  WRITET(0, A0, B0);
  LGKMB;

  // steady: 16 K-tiles, unrolled x2 for static reg-set selection
  #pragma unroll 1
  for (int jj=0; jj<7; jj++){
    const int t = 2*jj;
    // step t (even): load t+2 -> set0, write t+1 (set1) -> buf1, compute buf0
    LOADT(t+2, A0, B0);
    WAITVM("12");
    WRITET(1, A1, B1);
    COMP(0);
    LGKMB;
    // step t+1 (odd): load t+3 -> set1, write t+2 (set0) -> buf0, compute buf1
    LOADT(t+3, A1, B1);
    WAITVM("12");
    WRITET(0, A0, B0);
    COMP(1);
    LGKMB;
  }
  // t=14: tile15 (set1) is the last in flight
  WAITVM("0");
  WRITET(1, A1, B1);
  COMP(0);
  LGKMB;
  COMP(1);                               // t=15; epilogue touches no LDS

#undef LOADT
#undef WRITET

  const int colbase = n0 + wc*64;
  if (z < 2){
    const float* bias = z ? bk : bq;
    u16* outp = z ? Kp : Qp;
    const float scale = z ? 1.f : 0.125f*LOG2E;
    const int h = colbase >> 6;           // wave covers exactly one head
    float b1[2], b2[2], invr[2];
    #pragma unroll
    for (int nr=0;nr<2;nr++){
      int j2 = nr*16 + llo;
      b1[nr] = bias[colbase + j2];
      b2[nr] = bias[colbase + j2 + 32];
      invr[nr] = exp2f(-(float)j2 * 0.41524101186092033f) * INV2PI;  // 10000^{-j2/32}/(2pi)
    }
    #pragma unroll
    for (int mr=0;mr<4;mr++)
      #pragma unroll
      for (int r=0;r<4;r++){
        int row = m0 + wr*64 + mr*16 + lhi*4 + r;
        int b = row >> 11, l = row & 2047;
        u16* dst = outp + (((size_t)(b*CH + h)*CL + l) << 6);
        #pragma unroll
        for (int nr=0;nr<2;nr++){
          int j2 = nr*16 + llo;
          float x1 = (acc[mr][nr][r]   + b1[nr]) * scale;
          float x2 = (acc[mr][nr+2][r] + b2[nr]) * scale;
          float fr = fractf_((float)l * invr[nr]);
          float sn = sinrev(fr), cs = cosrev(fr);
          dst[j2]      = f2bf(x1*cs - x2*sn);
          dst[j2 + 32] = f2bf(x2*cs + x1*sn);
        }
      }
  } else {
    #pragma unroll
    for (int mr=0;mr<4;mr++)
      #pragma unroll
      for (int r=0;r<4;r++){
        int row = m0 + wr*64 + mr*16 + lhi*4 + r;
        float bvv = bv[row];
        #pragma unroll
        for (int nr=0;nr<4;nr++){
          int col = colbase + nr*16 + llo;
          Vt[(size_t)row*CM + col] = f2bf(acc[mr][nr][r] + bvv);
        }
      }
  }
}

// ---------------- output projection GEMM (fp32 out, bias per col) ----------------
// A = AO bf16 via global_load_lds ring-3; B = wo fp32 reg-staged (cast in staging).
__global__ __launch_bounds__(512) void gemm_out(
    const u16* __restrict__ A, const float* __restrict__ Btf,
    const float* __restrict__ bias, float* __restrict__ C)
{
  __shared__ u16 As[3][16384];   // 48KB
  __shared__ u16 Bs[2][8192];    // 32KB
  const int tid=threadIdx.x, lane=tid&63, wid=tid>>6;
  const int llo=lane&15, lhi=lane>>4;
  int bid = blockIdx.x;
  int xcd = bid&7, j = bid>>3;
  const int m0 = (xcd*4 + (j>>3))*256, n0 = (j&7)*128;   // 32 x 8 tiles of 256x128
  const int wr = wid>>1, wc = wid&1;
  const int rswA = llo&7;

  auto STAGEA = [&](int t, int buf){     // 4 gload_lds / thread
    #pragma unroll
    for (int i=0;i<4;i++){
      int c = tid + i*512, row=c>>3, sc=(c&7)^(row&7);
      __builtin_amdgcn_global_load_lds(GP(A + (size_t)(m0+row)*CE + t*64 + sc*8),
                                       LP(&As[buf][c*8]), 16, 0, 0);
    }
  };

  const float* bptr[2]; int bco[2];
  #pragma unroll
  for (int i=0;i<2;i++){
    int c = tid + i*512, row=c>>3, sc=(c&7)^(row&7);
    bptr[i] = Btf + (size_t)(n0+row)*CE + sc*8;
    bco[i] = c*8;
  }
  u32x4 B0[4], B1[4];

#define LOADB(T, RB) do{ \
  _Pragma("unroll") \
  for (int i=0;i<2;i++){ \
    asm volatile("global_load_dwordx4 %0, %2, off\n\tglobal_load_dwordx4 %1, %2, off offset:16" \
      : "=&v"(RB[2*i]), "=&v"(RB[2*i+1]) : "v"(bptr[i] + (size_t)(T)*64) : "memory"); \
  } \
}while(0)

#define WRITEB(BUF, RB) do{ \
  _Pragma("unroll") \
  for (int i=0;i<2;i++){ \
    u32x4 w; CVTW(w, RB[2*i], RB[2*i+1]); \
    *(u32x4*)&Bs[BUF][bco[i]] = w; \
  } \
}while(0)

  f32x4 acc[4][4] = {};

  auto COMP = [&](int abuf, int bbuf){
    const char* as = (const char*)As[abuf];
    const char* bs = (const char*)Bs[bbuf];
    #pragma unroll
    for (int ks=0; ks<2; ks++){
      bf16x8 af[4], bf_[4];
      #pragma unroll
      for (int mr=0;mr<4;mr++){
        int r = wr*64+mr*16+llo;
        af[mr] = as_bf(*(const uint4*)(as + r*128 + (((ks*4+lhi)^rswA)<<4)));
      }
      #pragma unroll
      for (int nr=0;nr<4;nr++){
        int r = wc*64+nr*16+llo;
        bf_[nr] = as_bf(*(const uint4*)(bs + r*128 + (((ks*4+lhi)^rswA)<<4)));
      }
      #pragma unroll
      for (int mr=0;mr<4;mr++)
        #pragma unroll
        for (int nr=0;nr<4;nr++)
          acc[mr][nr] = __builtin_amdgcn_mfma_f32_16x16x32_bf16(af[mr], bf_[nr], acc[mr][nr], 0,0,0);
    }
  };

  // prologue: A(0),B(0),A(1),B(1) in flight; confirm tile0 pair, write B0
  STAGEA(0,0); LOADB(0, B0);
  STAGEA(1,1); LOADB(1, B1);
  WAITVM("8");
  WRITEB(0, B0);
  LGKMB;

  #pragma unroll 1
  for (int jj=0; jj<7; jj++){
    const int t = 2*jj;
    STAGEA(t+2, (t+2)%3); LOADB(t+2, B0);
    WAITVM("8");
    WRITEB(1, B1);
    COMP(t%3, 0);
    LGKMB;
    STAGEA(t+3, (t+3)%3); LOADB(t+3, B1);
    WAITVM("8");
    WRITEB(0, B0);
    COMP((t+1)%3, 1);
    LGKMB;
  }
  WAITVM("0");
  WRITEB(1, B1);
  COMP(2, 0);          // t=14
  LGKMB;
  COMP(0, 1);          // t=15

#undef LOADB
#undef WRITEB

  #pragma unroll
  for (int mr=0;mr<4;mr++)
    #pragma unroll
    for (int nr=0;nr<4;nr++)
      #pragma unroll
      for (int r=0;r<4;r++){
        int row = m0 + wr*64 + mr*16 + lhi*4 + r;
        int col = n0 + wc*64 + nr*16 + llo;
        C[(size_t)row*CE + col] = acc[mr][nr][r] + bias[col];
      }
}

// ---------------- flash attention, swapped-operand 32x32, counted-vmcnt ring ----------------
// Qp,Kp: [B*H, L, D] bf16 (Q pre-scaled by 0.125*log2e). Vt: [E, CM] bf16. Out AO [B,L,E] bf16.
__global__ __launch_bounds__(256,2) void attn_kernel(
    const u16* __restrict__ Qp, const u16* __restrict__ Kp, const u16* __restrict__ Vt,
    const float* __restrict__ maskf, u16* __restrict__ AO)
{
  __shared__ u16 K_lds[4][4096];   // ring of [kv64][d64] swizzled tiles
  __shared__ u16 V_lds[4][4096];   // ring of [d64][kv64] swizzled tiles
  __shared__ float M_lds[2048];    // padding mask row (exp2 domain) for this batch
  const int bh = blockIdx.x;
  const int slot = blockIdx.y;
  const int b = bh >> 4, h = bh & 15;
  const int tid=threadIdx.x, lane=tid&63, wid=tid>>6;
  const int l31 = lane&31, hi = lane>>5;
  const u16* Qh = Qp + (size_t)bh*CL*CD;
  const u16* Kh = Kp + (size_t)bh*CL*CD;
  const u16* Vhd = Vt + (size_t)(h*CD)*CM + b*CL;

  // stage padding-mask row once (8KB). Issued FIRST so the t=0 vmcnt(8) covers it.
  #pragma unroll
  for (int i=0;i<2;i++)
    __builtin_amdgcn_global_load_lds(GP(maskf + b*CL + (i*256+tid)*4),
                                     LP(&M_lds[(i*256+tid)*4]), 16, 0, 0);

  auto STAGE = [&](int t, int buf){   // 4 gload_lds instructions per wave
    const u16* Ksrc = Kh + t*64*CD;
    const u16* Vsrc = Vhd + t*64;
    #pragma unroll
    for (int i=0;i<2;i++){
      int c = tid + i*256;
      int row = c>>3, sc = c&7;
      int c16 = sc ^ (row&7);
      __builtin_amdgcn_global_load_lds(GP(Ksrc + row*CD + c16*8),
                                       LP(&K_lds[buf][c*8]), 16, 0, 0);
      __builtin_amdgcn_global_load_lds(GP(Vsrc + (size_t)row*CM + c16*8),
                                       LP(&V_lds[buf][c*8]), 16, 0, 0);
    }
  };

  const int rowb = l31*128;            // LDS row byte base
  const int rsw  = (l31&7)<<4;
  const int qts2[2] = {15-slot, slot};

  for (int qi=0; qi<2; qi++){
    const int qt = qts2[qi];
    const int qw0 = qt*128 + wid*32;
    const int qlane = qw0 + l31;

    bf16x8 qf[4];
    #pragma unroll
    for (int c=0;c<4;c++)
      qf[c] = as_bf(*(const uint4*)(Qh + (size_t)qlane*CD + c*16 + hi*8));

    f32x16 o0 = {}, o1 = {};
    float m_r = -3e38f, l_r = 0.f;

    const int nt = qt*2 + 2;
    STAGE(0,0); STAGE(1,1);

    for (int t=0; t<nt; t++){
      // vmcnt ledger: entering iter t, {S(t),S(t+1)} = 8 outstanding (each 4/wave)
      if (t+2 < nt){ STAGE(t+2,(t+2)&3); WAITB("8"); }
      else if (t+1 < nt){ WAITB("4"); }
      else { WAITB("0"); }

      const int kv0 = t*64;
      const char* kb = (const char*)K_lds[t&3];
      const char* vb = (const char*)V_lds[t&3];

      // ---- padding mask (broadcast LDS reads; issue early to overlap MFMA)
      f32x4 cm[8];
      #pragma unroll
      for (int s2=0;s2<2;s2++)
        #pragma unroll
        for (int g=0; g<4; g++)
          cm[s2*4+g] = *(const f32x4*)&M_lds[kv0 + s2*32 + g*8 + hi*4];

      // ---- S^T = K @ Q^T  (two 32x32 tiles over kv); Q carries 0.125*log2e
      f32x16 s0 = {}, s1 = {};
      __builtin_amdgcn_s_setprio(1);
      #pragma unroll
      for (int c=0;c<4;c++){
        int cb = (c*32 + hi*16) ^ rsw;
        bf16x8 k0 = as_bf(*(const uint4*)(kb + rowb + cb));
        bf16x8 k1 = as_bf(*(const uint4*)(kb + 4096 + rowb + cb));
        s0 = __builtin_amdgcn_mfma_f32_32x32x16_bf16(k0, qf[c], s0, 0,0,0);
        s1 = __builtin_amdgcn_mfma_f32_32x32x16_bf16(k1, qf[c], s1, 0,0,0);
      }
      __builtin_amdgcn_s_setprio(0);

      // ---- v = s + mask (+ causal on diagonal tiles), in place (exp2 domain)
      if (kv0 + 63 > qw0){
        #pragma unroll
        for (int s2=0;s2<2;s2++){
          f32x16& sv = s2 ? s1 : s0;
          #pragma unroll
          for (int reg=0; reg<16; reg++){
            int k = kv0 + s2*32 + (reg&3) + (reg>>2)*8 + hi*4;
            float v = sv[reg] + cm[s2*4+(reg>>2)][reg&3];
            sv[reg] = (k > qlane) ? v + NEGBIG : v;
          }
        }
      } else {
        #pragma unroll
        for (int s2=0;s2<2;s2++){
          f32x16& sv = s2 ? s1 : s0;
          #pragma unroll
          for (int reg=0; reg<16; reg++)
            sv[reg] = sv[reg] + cm[s2*4+(reg>>2)][reg&3];
        }
      }

      // ---- row max (pairwise + v_max3 tree + partner swap)
      f32x16 mx;
      #pragma unroll
      for (int r=0;r<16;r++) mx[r] = fmaxf(s0[r], s1[r]);
      float a0 = max3f(mx[0],mx[1],mx[2]);
      float a1 = max3f(mx[3],mx[4],mx[5]);
      float a2 = max3f(mx[6],mx[7],mx[8]);
      float a3 = max3f(mx[9],mx[10],mx[11]);
      float a4 = max3f(mx[12],mx[13],mx[14]);
      float vmax = fmaxf(max3f(a0,a1,a2), max3f(a3,a4,mx[15]));
      vmax = fmaxf(vmax, __shfl_xor(vmax, 32));

      // ---- defer-max (T13): rescale only when max grew by > THR (log2 units)
      if (__any(vmax > m_r + 12.0f)){
        float mnew = fmaxf(m_r, vmax);
        float sc = fexp2(m_r - mnew);
        l_r *= sc;
        o0 *= sc; o1 *= sc;
        m_r = mnew;
      }

      // ---- p = exp2(v - m), in place (p <= 2^12)
      #pragma unroll
      for (int r=0;r<16;r++){
        s0[r] = fexp2(s0[r] - m_r);
        s1[r] = fexp2(s1[r] - m_r);
      }
      // ---- row sum
      f32x16 sm = s0 + s1;
      #pragma unroll
      for (int w=8; w>=1; w>>=1)
        #pragma unroll
        for (int r=0;r<w;r++) sm[r] = sm[r] + sm[r+w];
      float rsum = sm[0];
      rsum += __shfl_xor(rsum, 32);
      l_r += rsum;

      // ---- P -> bf16 B-fragments in-register (cvt_pk + permlane32_swap)
      u32 w_[16];
      #pragma unroll
      for (int s2=0;s2<2;s2++){
        f32x16& sv = s2 ? s1 : s0;
        #pragma unroll
        for (int c=0;c<2;c++){
          u32 a  = cvt_pk(sv[c*8+0], sv[c*8+1]);
          u32 bb = cvt_pk(sv[c*8+2], sv[c*8+3]);
          u32 cc = cvt_pk(sv[c*8+4], sv[c*8+5]);
          u32 dd = cvt_pk(sv[c*8+6], sv[c*8+7]);
          plswap(a, cc); plswap(bb, dd);
          int base = (s2*2+c)*4;
          w_[base+0]=a; w_[base+1]=bb; w_[base+2]=cc; w_[base+3]=dd;
        }
      }

      // ---- O^T += V^T @ P^T
      __builtin_amdgcn_s_setprio(1);
      #pragma unroll
      for (int kc=0; kc<4; kc++){
        bf16x8 pf = as_bf(make_uint4(w_[kc*4], w_[kc*4+1], w_[kc*4+2], w_[kc*4+3]));
        int cb = (kc*32 + hi*16) ^ rsw;
        bf16x8 v0 = as_bf(*(const uint4*)(vb + rowb + cb));
        bf16x8 v1 = as_bf(*(const uint4*)(vb + 4096 + rowb + cb));
        o0 = __builtin_amdgcn_mfma_f32_32x32x16_bf16(v0, pf, o0, 0,0,0);
        o1 = __builtin_amdgcn_mfma_f32_32x32x16_bf16(v1, pf, o1, 0,0,0);
      }
      __builtin_amdgcn_s_setprio(0);
      // no trailing barrier: ring depth 4 + per-iter barrier bounds wave skew safely
    }

    // ---- normalize + write O^T: lane has q=qlane, d = mt*32 + g*8 + hi*4 + {0..3}
    float inv = 1.f / l_r;
    u16* dst = AO + (size_t)(b*CL + qlane)*CE + h*CD;
    #pragma unroll
    for (int mt=0; mt<2; mt++){
      f32x16& ov = mt ? o1 : o0;
      #pragma unroll
      for (int g=0; g<4; g++){
        u32 lo  = cvt_pk(ov[g*4+0]*inv, ov[g*4+1]*inv);
        u32 hi2 = cvt_pk(ov[g*4+2]*inv, ov[g*4+3]*inv);
        *(uint2*)(dst + mt*32 + g*8 + hi*4) = make_uint2(lo, hi2);
      }
    }
    // drain + protect ring reuse by qi=1 prologue (and reset vmcnt ledger)
    __syncthreads();
  }
}

// ---------------- launcher ----------------
extern "C" void kernel_launch(void* const* d_in, const int* in_sizes, int n_in,
                              void* d_out, int out_size, void* d_ws, size_t ws_size,
                              hipStream_t stream) {
  const float* query = (const float*)d_in[0];
  const float* key_  = (const float*)d_in[1];
  const float* value = (const float*)d_in[2];
  const float* wq = (const float*)d_in[3];
  const float* bq = (const float*)d_in[4];
  const float* wk = (const float*)d_in[5];
  const float* bk = (const float*)d_in[6];
  const float* wv = (const float*)d_in[7];
  const float* bv = (const float*)d_in[8];
  const float* wo = (const float*)d_in[9];
  const float* bo = (const float*)d_in[10];
  const void*  kpm = d_in[11];

  char* ws = (char*)d_ws;
  constexpr size_t SZ_ME_BF = (size_t)CM*CE*2;    // 16 MiB
  constexpr size_t OFF_FLAG = 0;
  constexpr size_t OFF_MASKF= 256;
  constexpr size_t OFF_AO   = 65536;              // attn output, bf16 [B,L,E]
  constexpr size_t OFF_KP   = OFF_AO + SZ_ME_BF;
  constexpr size_t OFF_VT   = OFF_KP + SZ_ME_BF;  // Vt [1024][8192]
  constexpr size_t OFF_QP   = OFF_VT + SZ_ME_BF;

  int*   flag  = (int*)(ws + OFF_FLAG);
  float* maskf = (float*)(ws + OFF_MASKF);
  u16*  AO  = (u16*)(ws + OFF_AO);
  u16*  Kp  = (u16*)(ws + OFF_KP);
  u16*  Vt  = (u16*)(ws + OFF_VT);
  u16*  Qp  = (u16*)(ws + OFF_QP);

  detect_mask_kernel<<<1,256,0,stream>>>(kpm, flag);
  convert_mask_kernel<<<(CB*CL+255)/256,256,0,stream>>>(kpm, flag, maskf);

  // projections read fp32 inputs directly (cast fused into staging) — no cast pass
  gemm_qkv<<<dim3(256,3),512,0,stream>>>(query, key_, value, wq, wk, wv,
                                         bq, bk, bv, Qp, Kp, Vt);

  attn_kernel<<<dim3(CB*CH, 8),256,0,stream>>>(Qp, Kp, Vt, maskf, AO);

  gemm_out<<<256,512,0,stream>>>(AO, wo, bo, (float*)d_out);
}